// Round 18
// baseline (1552.946 us; speedup 1.0000x reference)
//
#include <hip/hip_runtime.h>

#define B_ 64
#define T_ 512
#define D_ 512
#define N_ 1024
#define G_ 4096   // 4*N

typedef _Float16 f16;
typedef __attribute__((ext_vector_type(8))) _Float16 f16x8;
typedef __attribute__((ext_vector_type(4))) float f32x4_t;
typedef unsigned long long u64;

static __device__ __forceinline__ f32x4_t mfma16(f16x8 a, f16x8 b, f32x4_t c) {
    return __builtin_amdgcn_mfma_f32_16x16x32_f16(a, b, c, 0, 0, 0);
}

static __device__ __forceinline__ float fsig(float x) {
    return 1.f / (1.f + __expf(-x));
}
static __device__ __forceinline__ float ftanh(float x) {
    return 1.f - 2.f / (__expf(2.f * x) + 1.f);
}

static __device__ __forceinline__ void lds_barrier() {
    asm volatile("s_waitcnt lgkmcnt(0)" ::: "memory");
    __builtin_amdgcn_s_barrier();
    __builtin_amdgcn_sched_barrier(0);
}

// workspace map: payload 4 replicas x 3 bufs x 128KB = 1.5MB; tags 32KB; xf.
#define PAYB    131072         // one payload buffer copy: [bg4][32KB]
#define REPS    0x60000        // replica stride = 3*PAYB
#define OFF_TAG 0x180000       // tags: [bg4][rep8][256] u32 = 32KB
#define OFF_XF  ((size_t)4 << 20)

// ---------------------------------------------------------------------------
// Phase 0: x -> f16 MFMA A-fragments (validated R15)
// ---------------------------------------------------------------------------
__global__ __launch_bounds__(256) void k_xfrag(const float* __restrict__ x,
                                               f16* __restrict__ xf) {
    __shared__ __align__(16) f16 xl[32768];   // 64 KB
    const int t = blockIdx.x;
    const int tid = threadIdx.x;

    for (int ch = tid; ch < 4096; ch += 256) {
        int b  = ch >> 6;
        int d0 = (ch & 63) << 3;
        const float* px = x + ((size_t)b * T_ + t) * D_ + d0;
        float4 v0 = *(const float4*)px;
        float4 v1 = *(const float4*)(px + 4);
        f16x8 s;
        s[0] = (f16)v0.x; s[1] = (f16)v0.y; s[2] = (f16)v0.z; s[3] = (f16)v0.w;
        s[4] = (f16)v1.x; s[5] = (f16)v1.y; s[6] = (f16)v1.z; s[7] = (f16)v1.w;
        int bg = b >> 4, ds = d0 >> 5;
        int lane = (((d0 >> 3) & 3) << 4) | (b & 15);
        *(f16x8*)(xl + (((bg * 16 + ds) * 64 + lane) << 3)) = s;
    }
    __syncthreads();
    f16* dst = xf + (size_t)t * 32768;
    for (int j = tid; j < 4096; j += 256)
        *(f16x8*)(dst + j * 8) = *(const f16x8*)(xl + j * 8);
}

// ---------------------------------------------------------------------------
// Phase 1: persistent recurrence (R17 structure, validated 1.50ms total).
// R18 deltas (drain hygiene; vmcnt retires IN ORDER on gfx9, so anything
// issued before the poll's tag-sample delays the first sample):
//  (a) out stores batched in LDS (thread-private slots), flushed as 8 nt
//      stores every 8th step -> HBM store-ack amortizes 900 -> ~110 cy/step.
//  (b) pacc double-buffered on t&1 -> ONE lds_barrier per step (2-buffer is
//      skew-safe: single barrier bounds intra-WG skew at 1 step).
// ---------------------------------------------------------------------------
__global__ __launch_bounds__(256, 1) void k_recur18(const float* __restrict__ W,
                                                    const float* __restrict__ bias,
                                                    const f16* __restrict__ xf,
                                                    char* __restrict__ wsb,
                                                    float* __restrict__ out) {
    __shared__ __align__(16) f16 wx[32768];     // 64 KB Wx B-fragments
    __shared__ float pacc[2][4][4][16][17];     // 34.8 KB (double-buffered)
    __shared__ float outb[4][8][64];            // 8 KB out batch

    const int wg  = blockIdx.x;
    const int tid = threadIdx.x;
    const int w   = tid >> 6;
    const int l   = tid & 63;
    const int bg  = wg >> 6;
    const int ci  = wg & 63;

    const int lb    = l & 15;
    const int dh    = l >> 4;
    const int nh    = ci * 16 + w * 4 + dh;
    const int bglob = bg * 16 + lb;

    unsigned* const tags = (unsigned*)(wsb + OFF_TAG);   // [bg][rep8][256]

    // ---- Wh B-fragments into registers (validated R3/R9/R10) ----
    f16x8 bf[4][8];
    {
        const int kq = l >> 4, ty = (l >> 2) & 3, dcl = l & 3;
        #pragma unroll
        for (int nt = 0; nt < 4; ++nt) {
            const int gc = ty * 1024 + ci * 16 + nt * 4 + dcl;
            #pragma unroll
            for (int kk = 0; kk < 8; ++kk) {
                #pragma unroll
                for (int i = 0; i < 8; ++i) {
                    int k = (w * 8 + kk) * 32 + kq * 8 + i;
                    bf[nt][kk][i] = (f16)W[(size_t)(D_ + k) * G_ + gc];
                }
            }
        }
    }

    // ---- Wx B-fragments into LDS (validated R15) ----
    for (int idx = tid; idx < 32768; idx += 256) {
        int gcl = idx & 63;
        int d   = idx >> 6;
        int ty  = gcl >> 4, c = gcl & 15;
        float wv = W[(size_t)d * G_ + ty * 1024 + ci * 16 + c];
        int ds = d >> 5, i = d & 7, kq = (d >> 3) & 3;
        int nt = c >> 2, dcl = c & 3;
        int lane = (kq << 4) | (ty << 2) | dcl;
        wx[(((ds * 4 + nt) * 64 + lane) << 3) + i] = (f16)wv;
    }

    const float b0 = bias[0 * 1024 + nh];
    const float b1 = bias[1 * 1024 + nh];
    const float b2 = bias[2 * 1024 + nh];
    const float b3 = bias[3 * 1024 + nh];

    // ---- producer/consumer addressing (R8/R10-validated slot layout) ----
    const int nq  = ci * 16 + w * 4;
    const int ksq = nq >> 5;
    const int q8  = (nq & 31) >> 3;
    const size_t st_off = (size_t)bg * 32768
                        + ((size_t)(ksq * 64 + q8 * 16 + lb) << 4)
                        + (size_t)(w & 1) * 8;
    const bool do_st = (dh == 0);
    const size_t ld_off = (size_t)bg * 32768 + ((size_t)(w * 8 * 64 + l) << 4);
    char* const myrep = wsb + (size_t)(ci & 3) * REPS;   // consumer replica

    // tags: producer (ci,w) writes 8 replicas (lanes 0-7); consumer reads ci&7
    unsigned* const tag_st = tags + (bg * 2048 + l * 256 + ci * 4 + w);  // l<8
    unsigned* const tag_ld = tags + (bg * 2048 + (ci & 7) * 256 + w * 64 + l);

    // ---- init: zero payload buf0 in all 4 replicas, release, tags = 1 ----
    if (do_st) {
        #pragma unroll
        for (int r = 0; r < 4; ++r)
            __hip_atomic_store((u64*)(wsb + (size_t)r * REPS + st_off), 0ull,
                               __ATOMIC_RELAXED, __HIP_MEMORY_SCOPE_AGENT);
    }
    asm volatile("s_waitcnt vmcnt(0)" ::: "memory");
    if (l < 8)
        __hip_atomic_store(tag_st, 1u, __ATOMIC_RELAXED, __HIP_MEMORY_SCOPE_AGENT);

    __syncthreads();   // also covers wx staging

    // prologue: x-fragments for t=0
    f16x8 xa[4];
    {
        const f16* p0 = xf + (size_t)bg * 8192 + ((size_t)(w * 4) * 64 + l) * 8;
        #pragma unroll
        for (int kk = 0; kk < 4; ++kk)
            xa[kk] = *(const f16x8*)(p0 + (size_t)kk * 512);
    }

    float cst = 0.f;
    int cur = 0, nxt = 1;

    for (int t = 0; t < T_; ++t) {
        const int pb = t & 1;

        // ---- Wx-MFMAs (poll-shadow region; validated R17) ----
        f32x4_t acc[4];
        #pragma unroll
        for (int nt = 0; nt < 4; ++nt) acc[nt] = f32x4_t{0.f, 0.f, 0.f, 0.f};
        #pragma unroll
        for (int kk = 0; kk < 4; ++kk) {
            #pragma unroll
            for (int nt = 0; nt < 4; ++nt) {
                f16x8 wb = *(const f16x8*)(wx + (((((w * 4 + kk) * 4) + nt) * 64 + l) << 3));
                acc[nt] = mfma16(xa[kk], wb, acc[nt]);
            }
        }

        // ---- poll own 64 producer-wave tags (replica ci&7) ----
        {
            const unsigned tgt = (unsigned)(t + 1);
            while (true) {
                unsigned v = __hip_atomic_load(tag_ld, __ATOMIC_RELAXED,
                                               __HIP_MEMORY_SCOPE_AGENT);
                if (__all(v >= tgt)) break;
                __builtin_amdgcn_s_sleep(1);
            }
        }

        // ---- payload: 8 x 16B coherent loads from replica ci&3 ----
        f16x8 af[8];
        {
            const char* pl = myrep + (size_t)cur * PAYB + ld_off;
            #pragma unroll
            for (int kk = 0; kk < 8; ++kk)
                asm volatile("global_load_dwordx4 %0, %1, off sc0 sc1"
                             : "=&v"(af[kk]) : "v"(pl + kk * 1024) : "memory");
        }
        asm volatile("s_waitcnt vmcnt(0)" ::: "memory");
        __builtin_amdgcn_sched_barrier(0);   // rule 18

        // ---- 32 Wh-MFMAs (B in regs) ----
        #pragma unroll
        for (int kk = 0; kk < 8; ++kk) {
            #pragma unroll
            for (int nt = 0; nt < 4; ++nt)
                acc[nt] = mfma16(af[kk], bf[nt][kk], acc[nt]);
        }

        // ---- cross-wave K-reduction via LDS (double-buffered pacc) ----
        {
            const int r0 = dh << 2;
            #pragma unroll
            for (int nt = 0; nt < 4; ++nt)
                #pragma unroll
                for (int j = 0; j < 4; ++j)
                    pacc[pb][w][nt][r0 + j][l & 15] = acc[nt][j];
        }
        lds_barrier();   // the ONE barrier per step

        float g0 = pacc[pb][0][w][lb][0 * 4 + dh] + pacc[pb][1][w][lb][0 * 4 + dh]
                 + pacc[pb][2][w][lb][0 * 4 + dh] + pacc[pb][3][w][lb][0 * 4 + dh] + b0;
        float g1 = pacc[pb][0][w][lb][1 * 4 + dh] + pacc[pb][1][w][lb][1 * 4 + dh]
                 + pacc[pb][2][w][lb][1 * 4 + dh] + pacc[pb][3][w][lb][1 * 4 + dh] + b1;
        float g2 = pacc[pb][0][w][lb][2 * 4 + dh] + pacc[pb][1][w][lb][2 * 4 + dh]
                 + pacc[pb][2][w][lb][2 * 4 + dh] + pacc[pb][3][w][lb][2 * 4 + dh] + b2;
        float g3 = pacc[pb][0][w][lb][3 * 4 + dh] + pacc[pb][1][w][lb][3 * 4 + dh]
                 + pacc[pb][2][w][lb][3 * 4 + dh] + pacc[pb][3][w][lb][3 * 4 + dh] + b3;

        float si = fsig(g0);
        float tj = ftanh(g1);
        float sf = fsig(g2 + 1.f);
        float so = fsig(g3);
        cst = cst * sf + si * tj;
        float h = ftanh(cst) * so;

        // ---- publish: 4 replica payload stores -> one ack -> 8 tag stores ----
        {
            unsigned hu = (unsigned)__builtin_bit_cast(unsigned short, (f16)h);
            unsigned ot = __shfl_xor(hu, 16);
            unsigned dw = (dh & 1) ? ((ot & 0xffffu) | (hu << 16))
                                   : ((hu & 0xffffu) | (ot << 16));
            unsigned dw2 = __shfl_xor(dw, 32);
            if (do_st && t < T_ - 1) {
                u64 val = (u64)dw | ((u64)dw2 << 32);
                #pragma unroll
                for (int r = 0; r < 4; ++r)
                    __hip_atomic_store(
                        (u64*)(wsb + (size_t)r * REPS + (size_t)nxt * PAYB + st_off),
                        val, __ATOMIC_RELAXED, __HIP_MEMORY_SCOPE_AGENT);
            }
        }
        asm volatile("s_waitcnt vmcnt(0)" ::: "memory");   // payload acked at LLC
        if (l < 8 && t < T_ - 1)
            __hip_atomic_store(tag_st, (unsigned)(t + 2),
                               __ATOMIC_RELAXED, __HIP_MEMORY_SCOPE_AGENT);

        // ---- out: stash in LDS (thread-private slot), flush every 8 steps ----
        outb[w][t & 7][l] = h;
        if ((t & 7) == 7) {
            #pragma unroll
            for (int j = 0; j < 8; ++j) {
                float hv = outb[w][j][l];
                __builtin_nontemporal_store(hv,
                    &out[((size_t)bglob * T_ + (t - 7 + j)) * N_ + nh]);
            }
        }

        // ---- x-fragment prefetch for t+1 (plain cached; rides the poll) ----
        if (t + 1 < T_) {
            const f16* pn = xf + (size_t)(t + 1) * 32768 + (size_t)bg * 8192
                          + ((size_t)(w * 4) * 64 + l) * 8;
            #pragma unroll
            for (int kk = 0; kk < 4; ++kk)
                xa[kk] = *(const f16x8*)(pn + (size_t)kk * 512);
        }

        cur = nxt;
        nxt = (nxt == 2) ? 0 : nxt + 1;
    }
}

// ---------------------------------------------------------------------------
extern "C" void kernel_launch(void* const* d_in, const int* in_sizes, int n_in,
                              void* d_out, int out_size, void* d_ws, size_t ws_size,
                              hipStream_t stream) {
    const float* x    = (const float*)d_in[0];
    const float* W    = (const float*)d_in[1];
    const float* bias = (const float*)d_in[2];
    float* out = (float*)d_out;

    char* ws = (char*)d_ws;
    f16*  xf = (f16*)(ws + OFF_XF);   // 32 MB of x fragments

    const size_t need = OFF_XF + (size_t)T_ * 32768 * sizeof(f16);
    if (ws_size < need) {
        hipMemsetAsync(d_out, 0, (size_t)out_size * sizeof(float), stream);
        return;
    }

    hipLaunchKernelGGL(k_xfrag, dim3(512), dim3(256), 0, stream, x, xf);

    // tag reset; re-executes on every graph replay -> deterministic start.
    hipMemsetAsync(ws + OFF_TAG, 0, 32768, stream);

    void* args[] = { (void*)&W, (void*)&bias, (void*)&xf, (void*)&ws, (void*)&out };
    hipError_t e = hipLaunchCooperativeKernel((void*)k_recur18, dim3(256), dim3(256),
                                              args, 0, stream);
    if (e != hipSuccess) {
        // ~107KB LDS -> 1 WG/CU, grid 256 == CU count: co-residency holds
        hipLaunchKernelGGL(k_recur18, dim3(256), dim3(256), 0, stream,
                           W, bias, xf, ws, out);
    }
}

// Round 19
// 1490.578 us; speedup vs baseline: 1.0418x; 1.0418x over previous
//
#include <hip/hip_runtime.h>

#define B_ 64
#define T_ 512
#define D_ 512
#define N_ 1024
#define G_ 4096   // 4*N

typedef _Float16 f16;
typedef __attribute__((ext_vector_type(8))) _Float16 f16x8;
typedef __attribute__((ext_vector_type(4))) float f32x4_t;
typedef unsigned long long u64;

static __device__ __forceinline__ f32x4_t mfma16(f16x8 a, f16x8 b, f32x4_t c) {
    return __builtin_amdgcn_mfma_f32_16x16x32_f16(a, b, c, 0, 0, 0);
}

static __device__ __forceinline__ float fsig(float x) {
    return 1.f / (1.f + __expf(-x));
}
static __device__ __forceinline__ float ftanh(float x) {
    return 1.f - 2.f / (__expf(2.f * x) + 1.f);
}

static __device__ __forceinline__ void lds_barrier() {
    asm volatile("s_waitcnt lgkmcnt(0)" ::: "memory");
    __builtin_amdgcn_s_barrier();
    __builtin_amdgcn_sched_barrier(0);
}

// workspace map: payload 4 replicas x 3 bufs x 128KB = 1.5MB; tags 32KB; xf.
#define PAYB    131072         // one payload buffer copy: [bg4][32KB]
#define REPS    0x60000        // replica stride = 3*PAYB
#define OFF_TAG 0x180000       // tags: [bg4][rep8][256] u32 = 32KB
#define OFF_XF  ((size_t)4 << 20)

// ---------------------------------------------------------------------------
// Phase 0: x -> f16 MFMA A-fragments (validated R15)
// ---------------------------------------------------------------------------
__global__ __launch_bounds__(256) void k_xfrag(const float* __restrict__ x,
                                               f16* __restrict__ xf) {
    __shared__ __align__(16) f16 xl[32768];   // 64 KB
    const int t = blockIdx.x;
    const int tid = threadIdx.x;

    for (int ch = tid; ch < 4096; ch += 256) {
        int b  = ch >> 6;
        int d0 = (ch & 63) << 3;
        const float* px = x + ((size_t)b * T_ + t) * D_ + d0;
        float4 v0 = *(const float4*)px;
        float4 v1 = *(const float4*)(px + 4);
        f16x8 s;
        s[0] = (f16)v0.x; s[1] = (f16)v0.y; s[2] = (f16)v0.z; s[3] = (f16)v0.w;
        s[4] = (f16)v1.x; s[5] = (f16)v1.y; s[6] = (f16)v1.z; s[7] = (f16)v1.w;
        int bg = b >> 4, ds = d0 >> 5;
        int lane = (((d0 >> 3) & 3) << 4) | (b & 15);
        *(f16x8*)(xl + (((bg * 16 + ds) * 64 + lane) << 3)) = s;
    }
    __syncthreads();
    f16* dst = xf + (size_t)t * 32768;
    for (int j = tid; j < 4096; j += 256)
        *(f16x8*)(dst + j * 8) = *(const f16x8*)(xl + j * 8);
}

// ---------------------------------------------------------------------------
// Phase 1: persistent recurrence — R17 structure VERBATIM (validated 1.50ms;
// R18's out-batching + single-barrier regressed and is reverted).
// R19 single delta: no s_sleep in the tag poll — with 8x tag replication the
// retry traffic is tiny (~64KB/round) and the sleep only added sampling
// quantization (up to 64cy/round) to the serial chain.
// ---------------------------------------------------------------------------
__global__ __launch_bounds__(256, 1) void k_recur19(const float* __restrict__ W,
                                                    const float* __restrict__ bias,
                                                    const f16* __restrict__ xf,
                                                    char* __restrict__ wsb,
                                                    float* __restrict__ out) {
    __shared__ __align__(16) f16 wx[32768];     // 64 KB Wx B-fragments
    __shared__ float pacc[4][4][16][17];        // 17.4 KB

    const int wg  = blockIdx.x;
    const int tid = threadIdx.x;
    const int w   = tid >> 6;
    const int l   = tid & 63;
    const int bg  = wg >> 6;
    const int ci  = wg & 63;

    const int lb    = l & 15;
    const int dh    = l >> 4;
    const int nh    = ci * 16 + w * 4 + dh;
    const int bglob = bg * 16 + lb;

    unsigned* const tags = (unsigned*)(wsb + OFF_TAG);   // [bg][rep8][256]

    // ---- Wh B-fragments into registers (validated R3/R9/R10) ----
    f16x8 bf[4][8];
    {
        const int kq = l >> 4, ty = (l >> 2) & 3, dcl = l & 3;
        #pragma unroll
        for (int nt = 0; nt < 4; ++nt) {
            const int gc = ty * 1024 + ci * 16 + nt * 4 + dcl;
            #pragma unroll
            for (int kk = 0; kk < 8; ++kk) {
                #pragma unroll
                for (int i = 0; i < 8; ++i) {
                    int k = (w * 8 + kk) * 32 + kq * 8 + i;
                    bf[nt][kk][i] = (f16)W[(size_t)(D_ + k) * G_ + gc];
                }
            }
        }
    }

    // ---- Wx B-fragments into LDS (validated R15) ----
    for (int idx = tid; idx < 32768; idx += 256) {
        int gcl = idx & 63;
        int d   = idx >> 6;
        int ty  = gcl >> 4, c = gcl & 15;
        float wv = W[(size_t)d * G_ + ty * 1024 + ci * 16 + c];
        int ds = d >> 5, i = d & 7, kq = (d >> 3) & 3;
        int nt = c >> 2, dcl = c & 3;
        int lane = (kq << 4) | (ty << 2) | dcl;
        wx[(((ds * 4 + nt) * 64 + lane) << 3) + i] = (f16)wv;
    }

    const float b0 = bias[0 * 1024 + nh];
    const float b1 = bias[1 * 1024 + nh];
    const float b2 = bias[2 * 1024 + nh];
    const float b3 = bias[3 * 1024 + nh];

    // ---- producer/consumer addressing (R8/R10-validated slot layout) ----
    const int nq  = ci * 16 + w * 4;
    const int ksq = nq >> 5;
    const int q8  = (nq & 31) >> 3;
    const size_t st_off = (size_t)bg * 32768
                        + ((size_t)(ksq * 64 + q8 * 16 + lb) << 4)
                        + (size_t)(w & 1) * 8;
    const bool do_st = (dh == 0);
    const size_t ld_off = (size_t)bg * 32768 + ((size_t)(w * 8 * 64 + l) << 4);
    char* const myrep = wsb + (size_t)(ci & 3) * REPS;   // consumer replica

    // tags: producer (ci,w) writes 8 replicas (lanes 0-7); consumer reads ci&7
    unsigned* const tag_st = tags + (bg * 2048 + l * 256 + ci * 4 + w);  // l<8
    unsigned* const tag_ld = tags + (bg * 2048 + (ci & 7) * 256 + w * 64 + l);

    // ---- init: zero payload buf0 in all 4 replicas, release, tags = 1 ----
    if (do_st) {
        #pragma unroll
        for (int r = 0; r < 4; ++r)
            __hip_atomic_store((u64*)(wsb + (size_t)r * REPS + st_off), 0ull,
                               __ATOMIC_RELAXED, __HIP_MEMORY_SCOPE_AGENT);
    }
    asm volatile("s_waitcnt vmcnt(0)" ::: "memory");
    if (l < 8)
        __hip_atomic_store(tag_st, 1u, __ATOMIC_RELAXED, __HIP_MEMORY_SCOPE_AGENT);

    __syncthreads();   // also covers wx staging

    // prologue: x-fragments for t=0
    f16x8 xa[4];
    {
        const f16* p0 = xf + (size_t)bg * 8192 + ((size_t)(w * 4) * 64 + l) * 8;
        #pragma unroll
        for (int kk = 0; kk < 4; ++kk)
            xa[kk] = *(const f16x8*)(p0 + (size_t)kk * 512);
    }

    float cst = 0.f;
    int cur = 0, nxt = 1;
    float  h_prev = 0.f;
    size_t oprev  = 0;

    for (int t = 0; t < T_; ++t) {
        if (t > 0)
            __builtin_nontemporal_store(h_prev, &out[oprev]);

        // ---- Wx-MFMAs hoisted: run in the poll's shadow (validated R17) ----
        f32x4_t acc[4];
        #pragma unroll
        for (int nt = 0; nt < 4; ++nt) acc[nt] = f32x4_t{0.f, 0.f, 0.f, 0.f};
        #pragma unroll
        for (int kk = 0; kk < 4; ++kk) {
            #pragma unroll
            for (int nt = 0; nt < 4; ++nt) {
                f16x8 wb = *(const f16x8*)(wx + (((((w * 4 + kk) * 4) + nt) * 64 + l) << 3));
                acc[nt] = mfma16(xa[kk], wb, acc[nt]);
            }
        }

        // ---- poll own 64 producer-wave tags (replica ci&7), no sleep ----
        {
            const unsigned tgt = (unsigned)(t + 1);
            while (true) {
                unsigned v = __hip_atomic_load(tag_ld, __ATOMIC_RELAXED,
                                               __HIP_MEMORY_SCOPE_AGENT);
                if (__all(v >= tgt)) break;
            }
        }

        // ---- payload: 8 x 16B coherent loads from replica ci&3 ----
        f16x8 af[8];
        {
            const char* pl = myrep + (size_t)cur * PAYB + ld_off;
            #pragma unroll
            for (int kk = 0; kk < 8; ++kk)
                asm volatile("global_load_dwordx4 %0, %1, off sc0 sc1"
                             : "=&v"(af[kk]) : "v"(pl + kk * 1024) : "memory");
        }
        asm volatile("s_waitcnt vmcnt(0)" ::: "memory");
        __builtin_amdgcn_sched_barrier(0);   // rule 18

        // ---- 32 Wh-MFMAs (B in regs) ----
        #pragma unroll
        for (int kk = 0; kk < 8; ++kk) {
            #pragma unroll
            for (int nt = 0; nt < 4; ++nt)
                acc[nt] = mfma16(af[kk], bf[nt][kk], acc[nt]);
        }

        // ---- cross-wave K-reduction via LDS ----
        {
            const int r0 = dh << 2;
            #pragma unroll
            for (int nt = 0; nt < 4; ++nt)
                #pragma unroll
                for (int j = 0; j < 4; ++j)
                    pacc[w][nt][r0 + j][l & 15] = acc[nt][j];
        }
        lds_barrier();

        float g0 = pacc[0][w][lb][0 * 4 + dh] + pacc[1][w][lb][0 * 4 + dh]
                 + pacc[2][w][lb][0 * 4 + dh] + pacc[3][w][lb][0 * 4 + dh] + b0;
        float g1 = pacc[0][w][lb][1 * 4 + dh] + pacc[1][w][lb][1 * 4 + dh]
                 + pacc[2][w][lb][1 * 4 + dh] + pacc[3][w][lb][1 * 4 + dh] + b1;
        float g2 = pacc[0][w][lb][2 * 4 + dh] + pacc[1][w][lb][2 * 4 + dh]
                 + pacc[2][w][lb][2 * 4 + dh] + pacc[3][w][lb][2 * 4 + dh] + b2;
        float g3 = pacc[0][w][lb][3 * 4 + dh] + pacc[1][w][lb][3 * 4 + dh]
                 + pacc[2][w][lb][3 * 4 + dh] + pacc[3][w][lb][3 * 4 + dh] + b3;

        float si = fsig(g0);
        float tj = ftanh(g1);
        float sf = fsig(g2 + 1.f);
        float so = fsig(g3);
        cst = cst * sf + si * tj;
        float h = ftanh(cst) * so;

        // ---- publish: 4 replica payload stores -> one ack -> 8 tag stores ----
        {
            unsigned hu = (unsigned)__builtin_bit_cast(unsigned short, (f16)h);
            unsigned ot = __shfl_xor(hu, 16);
            unsigned dw = (dh & 1) ? ((ot & 0xffffu) | (hu << 16))
                                   : ((hu & 0xffffu) | (ot << 16));
            unsigned dw2 = __shfl_xor(dw, 32);
            if (do_st && t < T_ - 1) {
                u64 val = (u64)dw | ((u64)dw2 << 32);
                #pragma unroll
                for (int r = 0; r < 4; ++r)
                    __hip_atomic_store(
                        (u64*)(wsb + (size_t)r * REPS + (size_t)nxt * PAYB + st_off),
                        val, __ATOMIC_RELAXED, __HIP_MEMORY_SCOPE_AGENT);
            }
        }
        asm volatile("s_waitcnt vmcnt(0)" ::: "memory");   // payload acked at LLC
        if (l < 8 && t < T_ - 1)
            __hip_atomic_store(tag_st, (unsigned)(t + 2),
                               __ATOMIC_RELAXED, __HIP_MEMORY_SCOPE_AGENT);

        // ---- x-fragment prefetch for t+1 (plain cached; rides the poll) ----
        if (t + 1 < T_) {
            const f16* pn = xf + (size_t)(t + 1) * 32768 + (size_t)bg * 8192
                          + ((size_t)(w * 4) * 64 + l) * 8;
            #pragma unroll
            for (int kk = 0; kk < 4; ++kk)
                xa[kk] = *(const f16x8*)(pn + (size_t)kk * 512);
        }

        h_prev = h;
        oprev  = ((size_t)bglob * T_ + t) * N_ + nh;

        lds_barrier();   // pacc anti-dependency
        cur = nxt;
        nxt = (nxt == 2) ? 0 : nxt + 1;
    }
    __builtin_nontemporal_store(h_prev, &out[oprev]);
}

// ---------------------------------------------------------------------------
extern "C" void kernel_launch(void* const* d_in, const int* in_sizes, int n_in,
                              void* d_out, int out_size, void* d_ws, size_t ws_size,
                              hipStream_t stream) {
    const float* x    = (const float*)d_in[0];
    const float* W    = (const float*)d_in[1];
    const float* bias = (const float*)d_in[2];
    float* out = (float*)d_out;

    char* ws = (char*)d_ws;
    f16*  xf = (f16*)(ws + OFF_XF);   // 32 MB of x fragments

    const size_t need = OFF_XF + (size_t)T_ * 32768 * sizeof(f16);
    if (ws_size < need) {
        hipMemsetAsync(d_out, 0, (size_t)out_size * sizeof(float), stream);
        return;
    }

    hipLaunchKernelGGL(k_xfrag, dim3(512), dim3(256), 0, stream, x, xf);

    // tag reset; re-executes on every graph replay -> deterministic start.
    hipMemsetAsync(ws + OFF_TAG, 0, 32768, stream);

    void* args[] = { (void*)&W, (void*)&bias, (void*)&xf, (void*)&ws, (void*)&out };
    hipError_t e = hipLaunchCooperativeKernel((void*)k_recur19, dim3(256), dim3(256),
                                              args, 0, stream);
    if (e != hipSuccess) {
        // ~84KB LDS -> 1 WG/CU, grid 256 == CU count: co-residency holds
        hipLaunchKernelGGL(k_recur19, dim3(256), dim3(256), 0, stream,
                           W, bias, xf, ws, out);
    }
}